// Round 7
// baseline (171.517 us; speedup 1.0000x reference)
//
#include <hip/hip_runtime.h>

#define N_NODES 50000
#define N_EDGES 800000
#define BSHIFT 6                                   // 64 nodes per bucket
#define NBKT   ((N_NODES + 63) >> BSHIFT)          // 782
#define CAP    2048                                // padded slots per bucket
#define CHUNK_EDGES 8192
#define NBIN_BLOCKS ((N_EDGES + CHUNK_EDGES - 1) / CHUNK_EDGES)  // 98
#define NB1    ((N_NODES + 3) / 4)                 // 12500 node-blocks per slice
#define N_PAD  50048                               // padded node count (slice regions)

typedef __attribute__((ext_vector_type(8))) short short8;   // 8 bf16 (4 VGPRs)
typedef __attribute__((ext_vector_type(4))) float f32x4;    // MFMA acc

__device__ __forceinline__ int load_idx(const void* ei, int is64, long long pos) {
  return is64 ? (int)((const long long*)ei)[pos] : ((const int*)ei)[pos];
}

// bf16 (RNE) pack/unpack helpers
__device__ __forceinline__ unsigned bfr(float f) {
  unsigned u = __float_as_uint(f);
  return (u + 0x7FFFu + ((u >> 16) & 1u)) >> 16;
}
__device__ __forceinline__ unsigned bfpk(float lo, float hi) {
  return bfr(lo) | (bfr(hi) << 16);
}
#define ACC_BF4(acc, u)                                                    \
  acc.x += __uint_as_float((u).x << 16);                                   \
  acc.y += __uint_as_float((u).x & 0xffff0000u);                           \
  acc.z += __uint_as_float((u).y << 16);                                   \
  acc.w += __uint_as_float((u).y & 0xffff0000u);

// ---------------------------------------------------------------------------
// prep: cast W1/W2 to bf16, native [o][k] layout (W2 padded to 48 rows).
// ---------------------------------------------------------------------------
__global__ __launch_bounds__(256) void prep_kernel(const float* __restrict__ W1,
                                                   const float* __restrict__ W2,
                                                   unsigned short* __restrict__ W1bf,
                                                   unsigned short* __restrict__ W2bf) {
  int j = blockIdx.x * 256 + threadIdx.x;        // [0, 22528)
  if (j < 128 * 128) {
    W1bf[j] = (unsigned short)bfr(W1[j]);
  } else {
    int jj = j - 128 * 128;                      // [0, 6144)
    int c = jj >> 7, k = jj & 127;
    W2bf[jj] = (c < 40) ? (unsigned short)bfr(W2[c * 128 + k]) : 0;
  }
}

// ---------------------------------------------------------------------------
// binPlace2: single-pass bucket partition. Per-block: dtype detect (wave 0),
// LDS bucket histogram, ONE global reservation per bucket, place packed edges
// into padded bucket regions binned[bk*CAP ...]. pk = src|dstlow<<16|bk<<22.
// ---------------------------------------------------------------------------
__global__ __launch_bounds__(256) void binPlace2_kernel(const void* __restrict__ ei,
                                                        int* __restrict__ resv,
                                                        unsigned* __restrict__ binned) {
  __shared__ int cnt[NBKT];
  __shared__ int lbase[NBKT];
  __shared__ int sflag;
  int tid = threadIdx.x;
  if (tid < 64) {
    const long long* e64 = (const long long*)ei;
    long long v = e64[tid];
    unsigned long long m = __ballot(v >= 0 && v < N_NODES);
    if (tid == 0) sflag = (m == ~0ull) ? 1 : 0;
  }
  for (int i = tid; i < NBKT; i += 256) cnt[i] = 0;
  __syncthreads();
  int f = sflag;
  long long base = (long long)blockIdx.x * CHUNK_EDGES;
  unsigned pk[CHUNK_EDGES / 256];
  #pragma unroll
  for (int it = 0; it < CHUNK_EDGES / 256; ++it) {
    long long e = base + it * 256 + tid;
    unsigned p = 0xFFFFFFFFu;
    if (e < N_EDGES) {
      int src = load_idx(ei, f, e);
      int dst = load_idx(ei, f, (long long)N_EDGES + e);
      int bk = dst >> BSHIFT;
      p = (unsigned)src | ((unsigned)(dst & 63) << 16) | ((unsigned)bk << 22);
      atomicAdd(&cnt[bk], 1);
    }
    pk[it] = p;
  }
  __syncthreads();
  for (int i = tid; i < NBKT; i += 256) {
    int c = cnt[i];
    lbase[i] = c ? (i * CAP + atomicAdd(&resv[i], c)) : 0;
    cnt[i] = 0;                                   // reuse as local cursor
  }
  __syncthreads();
  #pragma unroll
  for (int it = 0; it < CHUNK_EDGES / 256; ++it) {
    unsigned p = pk[it];
    if (p != 0xFFFFFFFFu) {
      int bk = p >> 22;
      int off = atomicAdd(&cnt[bk], 1);
      binned[lbase[bk] + off] = p & 0x3FFFFFu;    // src | dstlow<<16
    }
  }
}

// ---------------------------------------------------------------------------
// bucketScan: exclusive scan of 782 bucket totals (resv) -> gbase.
// ---------------------------------------------------------------------------
__global__ __launch_bounds__(1024) void bucketScan_kernel(const int* __restrict__ resv,
                                                          int* __restrict__ gbase,
                                                          int* __restrict__ rowptr) {
  __shared__ int s[1024];
  int tid = threadIdx.x;
  s[tid] = (tid < NBKT) ? resv[tid] : 0;
  __syncthreads();
  for (int off = 1; off < 1024; off <<= 1) {
    int t = (tid >= off) ? s[tid - off] : 0;
    __syncthreads();
    s[tid] += t;
    __syncthreads();
  }
  int excl = (tid == 0) ? 0 : s[tid - 1];
  if (tid < NBKT) gbase[tid] = excl;
  if (tid == NBKT) gbase[NBKT] = s[NBKT - 1];   // == N_EDGES
  if (tid == 0) rowptr[N_NODES] = N_EDGES;
}

// ---------------------------------------------------------------------------
// csrBuild: one block per bucket. LDS node histogram + serial scan -> rowptr;
// compact padded bucket region into col (ushort src).
// ---------------------------------------------------------------------------
__global__ __launch_bounds__(256) void csrBuild_kernel(const unsigned* __restrict__ binned,
                                                       const int* __restrict__ gbase,
                                                       int* __restrict__ rowptr,
                                                       unsigned short* __restrict__ col) {
  __shared__ int ncnt[64];
  __shared__ int ncur[64];
  int b = blockIdx.x, tid = threadIdx.x;
  int gb = gbase[b];
  int c = gbase[b + 1] - gb;
  if (tid < 64) ncnt[tid] = 0;
  __syncthreads();
  const unsigned* bb = binned + (size_t)b * CAP;
  for (int i = tid; i < c; i += 256)
    atomicAdd(&ncnt[(bb[i] >> 16) & 63], 1);
  __syncthreads();
  if (tid == 0) {
    int a = gb;
    #pragma unroll
    for (int j = 0; j < 64; ++j) { int t = ncnt[j]; ncur[j] = a; a += t; }
  }
  __syncthreads();
  int node0 = b << BSHIFT;
  if (tid < 64 && node0 + tid < N_NODES) rowptr[node0 + tid] = ncur[tid];
  __syncthreads();
  for (int i = tid; i < c; i += 256) {
    unsigned p = bb[i];
    int slot = atomicAdd(&ncur[(p >> 16) & 63], 1);
    col[slot] = (unsigned short)(p & 0xFFFFu);
  }
}

// ---------------------------------------------------------------------------
// gather1 (slice-phased): h1[n][slice*32..+32) = relu(Y_s[n] + sum Y_s[src]).
// Y stored slice-major: 4 regions of N_PAD x 32 bf16 (3.2MB each, fits L2).
// Grid = 4 slices (slow) x 12500 node-blocks; wave = 1 node; 8 edge-groups
// x 8 lanes x uint2 -> one 64B line per edge.
// ---------------------------------------------------------------------------
__global__ __launch_bounds__(256) void gather1_kernel(const unsigned short* __restrict__ Ys,
                                                      const int* __restrict__ rowptr,
                                                      const unsigned short* __restrict__ col,
                                                      unsigned short* __restrict__ h1bf) {
  int bid = blockIdx.x;
  int slice = bid / NB1;
  int nb = bid - slice * NB1;
  int w = nb * 4 + (threadIdx.x >> 6);
  if (w >= N_NODES) return;
  int lane = threadIdx.x & 63;
  int g = lane >> 3;        // edge group 0..7
  int s = lane & 7;         // uint2 slot within 64B slice row
  const uint2* Y2 = (const uint2*)(Ys + (size_t)slice * N_PAD * 32);
  float4 acc = make_float4(0.f, 0.f, 0.f, 0.f);
  if (g == 0) {
    uint2 u = Y2[(size_t)w * 8 + s];
    ACC_BF4(acc, u);
  }
  int i = rowptr[w] + g, end = rowptr[w + 1];
  for (; i < end; i += 8) {
    int src = col[i];
    uint2 u = Y2[(size_t)src * 8 + s];
    ACC_BF4(acc, u);
  }
  acc.x += __shfl_xor(acc.x, 8);
  acc.y += __shfl_xor(acc.y, 8);
  acc.z += __shfl_xor(acc.z, 8);
  acc.w += __shfl_xor(acc.w, 8);
  acc.x += __shfl_xor(acc.x, 16);
  acc.y += __shfl_xor(acc.y, 16);
  acc.z += __shfl_xor(acc.z, 16);
  acc.w += __shfl_xor(acc.w, 16);
  acc.x += __shfl_xor(acc.x, 32);
  acc.y += __shfl_xor(acc.y, 32);
  acc.z += __shfl_xor(acc.z, 32);
  acc.w += __shfl_xor(acc.w, 32);
  if (lane < 8) {
    uint2 p;
    p.x = bfpk(fmaxf(acc.x, 0.f), fmaxf(acc.y, 0.f));
    p.y = bfpk(fmaxf(acc.z, 0.f), fmaxf(acc.w, 0.f));
    ((uint2*)h1bf)[(size_t)w * 32 + slice * 8 + s] = p;
  }
}

// ---------------------------------------------------------------------------
// gather2: out[n] = Z[n] + sum_src Z[src]; Z bf16, 40/row (10 uint2); out f32.
// Z is 4MB -> L2-resident already.
// ---------------------------------------------------------------------------
__global__ __launch_bounds__(256) void gather2_kernel(const unsigned short* __restrict__ Zbf,
                                                      const int* __restrict__ rowptr,
                                                      const unsigned short* __restrict__ col,
                                                      float* __restrict__ outp) {
  int w = (blockIdx.x * 256 + threadIdx.x) >> 6;
  if (w >= N_NODES) return;
  int lane = threadIdx.x & 63;
  int h = lane >> 4;
  int q = lane & 15;
  bool act = q < 10;
  const uint2* Z2 = (const uint2*)Zbf;
  float4 acc = make_float4(0.f, 0.f, 0.f, 0.f);
  if (h == 0 && act) {
    uint2 u = Z2[(size_t)w * 10 + q];
    ACC_BF4(acc, u);
  }
  int i = rowptr[w] + h, end = rowptr[w + 1];
  for (; i + 4 < end; i += 8) {
    int s0 = col[i], s1 = col[i + 4];
    if (act) {
      uint2 u0 = Z2[(size_t)s0 * 10 + q];
      uint2 u1 = Z2[(size_t)s1 * 10 + q];
      ACC_BF4(acc, u0); ACC_BF4(acc, u1);
    }
  }
  for (; i < end; i += 4) {
    int s0 = col[i];
    if (act) {
      uint2 u0 = Z2[(size_t)s0 * 10 + q];
      ACC_BF4(acc, u0);
    }
  }
  acc.x += __shfl_xor(acc.x, 16);
  acc.y += __shfl_xor(acc.y, 16);
  acc.z += __shfl_xor(acc.z, 16);
  acc.w += __shfl_xor(acc.w, 16);
  acc.x += __shfl_xor(acc.x, 32);
  acc.y += __shfl_xor(acc.y, 32);
  acc.z += __shfl_xor(acc.z, 32);
  acc.w += __shfl_xor(acc.w, 32);
  if (h == 0 && act)
    ((float4*)outp)[(size_t)w * 10 + q] = acc;
}

// ---------------------------------------------------------------------------
// MFMA GEMM1: Y[n][o] = sum_k x[n][k]*W1[o][k]. Epilogue writes SLICE-MAJOR
// Ys: 4 regions of [N_PAD][32] bf16.
// ---------------------------------------------------------------------------
__global__ __launch_bounds__(256) void gemm1_kernel(const float* __restrict__ xin,
                                                    const unsigned short* __restrict__ W1bf,
                                                    unsigned short* __restrict__ Ysbf) {
  __shared__ unsigned short Ysh[64 * 128];
  int tid = threadIdx.x;
  int wave = tid >> 6, lane = tid & 63;
  int rl = lane & 15, kg = lane >> 4;      // kg = 0..3
  int n0 = blockIdx.x * 64;
  int rowg = n0 + wave * 16 + rl;
  int row = (rowg < N_NODES) ? rowg : (N_NODES - 1);
  f32x4 acc[8];
  #pragma unroll
  for (int t = 0; t < 8; ++t) acc[t] = (f32x4)(0.f);
  #pragma unroll
  for (int kk = 0; kk < 4; ++kk) {
    int k0 = kk * 32 + kg * 8;
    const float* xr = xin + (size_t)row * 128 + k0;
    float4 a0 = *(const float4*)xr;
    float4 a1 = *(const float4*)(xr + 4);
    short8 a;
    a[0] = (short)bfr(a0.x); a[1] = (short)bfr(a0.y);
    a[2] = (short)bfr(a0.z); a[3] = (short)bfr(a0.w);
    a[4] = (short)bfr(a1.x); a[5] = (short)bfr(a1.y);
    a[6] = (short)bfr(a1.z); a[7] = (short)bfr(a1.w);
    #pragma unroll
    for (int t = 0; t < 8; ++t) {
      short8 b = *(const short8*)(W1bf + (t * 16 + rl) * 128 + k0);
      acc[t] = __builtin_amdgcn_mfma_f32_16x16x32_bf16(a, b, acc[t], 0, 0, 0);
    }
  }
  // C/D: col = rl, row = kg*4 + reg (within wave's 16 rows)
  #pragma unroll
  for (int t = 0; t < 8; ++t) {
    #pragma unroll
    for (int reg = 0; reg < 4; ++reg)
      Ysh[(wave * 16 + kg * 4 + reg) * 128 + t * 16 + rl] =
          (unsigned short)bfr(acc[t][reg]);
  }
  __syncthreads();
  int rows = N_NODES - n0; if (rows > 64) rows = 64;
  uint4* dstb = (uint4*)Ysbf;               // slice region = N_PAD*4 uint4
  const uint4* srcb = (const uint4*)Ysh;
  for (int i = tid; i < rows * 16; i += 256) {
    int r = i >> 4, j = i & 15;
    int slice = j >> 2, q = j & 3;
    dstb[(size_t)slice * (N_PAD * 4) + (size_t)(n0 + r) * 4 + q] = srcb[i];
  }
}

// ---------------------------------------------------------------------------
// MFMA GEMM2: Z[n][c] = sum_k h1[n][k]*W2[c][k], c<40 (3 tiles, padded 48).
// ---------------------------------------------------------------------------
__global__ __launch_bounds__(256) void gemm2_kernel(const unsigned short* __restrict__ h1bf,
                                                    const unsigned short* __restrict__ W2bf,
                                                    unsigned short* __restrict__ Zbf) {
  __shared__ unsigned short Zsh[64 * 40];
  int tid = threadIdx.x;
  int wave = tid >> 6, lane = tid & 63;
  int rl = lane & 15, kg = lane >> 4;
  int n0 = blockIdx.x * 64;
  int rowg = n0 + wave * 16 + rl;
  int row = (rowg < N_NODES) ? rowg : (N_NODES - 1);
  f32x4 acc[3];
  #pragma unroll
  for (int t = 0; t < 3; ++t) acc[t] = (f32x4)(0.f);
  #pragma unroll
  for (int kk = 0; kk < 4; ++kk) {
    int k0 = kk * 32 + kg * 8;
    short8 a = *(const short8*)(h1bf + (size_t)row * 128 + k0);
    #pragma unroll
    for (int t = 0; t < 3; ++t) {
      short8 b = *(const short8*)(W2bf + (t * 16 + rl) * 128 + k0);
      acc[t] = __builtin_amdgcn_mfma_f32_16x16x32_bf16(a, b, acc[t], 0, 0, 0);
    }
  }
  #pragma unroll
  for (int t = 0; t < 3; ++t) {
    int c = t * 16 + rl;
    if (c < 40) {
      #pragma unroll
      for (int reg = 0; reg < 4; ++reg)
        Zsh[(wave * 16 + kg * 4 + reg) * 40 + c] = (unsigned short)bfr(acc[t][reg]);
    }
  }
  __syncthreads();
  int rows = N_NODES - n0; if (rows > 64) rows = 64;
  unsigned* dst = (unsigned*)Zbf + (size_t)n0 * 20;
  const unsigned* src = (const unsigned*)Zsh;
  for (int i = tid; i < rows * 20; i += 256) dst[i] = src[i];
}

// ---------------------------------------------------------------------------
extern "C" void kernel_launch(void* const* d_in, const int* in_sizes, int n_in,
                              void* d_out, int out_size, void* d_ws, size_t ws_size,
                              hipStream_t stream) {
  const float* x  = (const float*)d_in[0];
  const void*  ei = d_in[1];
  const float* W1 = (const float*)d_in[2];
  const float* W2 = (const float*)d_in[3];
  float* out = (float*)d_out;

  // ws layout (4-byte units)
  int* resv   = (int*)d_ws;                         // 1024 (memset to 0)
  int* gbase  = resv + 1024;                        // 1024 (783 used)
  int* rowptr = gbase + 1024;                       // 50176 (50001 used)
  unsigned* binned = (unsigned*)(rowptr + 50176);   // NBKT*CAP = 1,601,536
  unsigned short* col  = (unsigned short*)(binned + (size_t)NBKT * CAP); // 800000 ushort
  unsigned short* Ysbf = col + N_EDGES;             // 4 * N_PAD * 32 bf16 (12.8MB)
  unsigned short* h1bf = Ysbf + (size_t)4 * N_PAD * 32;  // 6.4M bf16
  unsigned short* W1bf = h1bf + (size_t)N_NODES * 128;   // 16384 bf16
  unsigned short* W2bf = W1bf + 128 * 128;          // 48*128 bf16 (padded)
  unsigned short* Zbf  = Ysbf;                      // Z reuses dead Ys region

  hipMemsetAsync(resv, 0, 1024 * sizeof(int), stream);
  prep_kernel<<<88, 256, 0, stream>>>(W1, W2, W1bf, W2bf);
  binPlace2_kernel<<<NBIN_BLOCKS, 256, 0, stream>>>(ei, resv, binned);
  bucketScan_kernel<<<1, 1024, 0, stream>>>(resv, gbase, rowptr);
  csrBuild_kernel<<<NBKT, 256, 0, stream>>>(binned, gbase, rowptr, col);

  // Layer 1 (commuted): Ys = x @ W1^T (MFMA, slice-major bf16);
  // h1 = relu(Ys + A*Ys) (bf16, slice-phased gather)
  gemm1_kernel<<<(N_NODES + 63) / 64, 256, 0, stream>>>(x, W1bf, Ysbf);
  gather1_kernel<<<4 * NB1, 256, 0, stream>>>(Ysbf, rowptr, col, h1bf);

  // Layer 2 (commuted): Z = h1 @ W2^T (MFMA, bf16) ; out = Z + A*Z (f32)
  gemm2_kernel<<<(N_NODES + 63) / 64, 256, 0, stream>>>(h1bf, W2bf, Zbf);
  gather2_kernel<<<(N_NODES * 64) / 256, 256, 0, stream>>>(Zbf, rowptr, col, out);
}

// Round 8
// 128.407 us; speedup vs baseline: 1.3357x; 1.3357x over previous
//
#include <hip/hip_runtime.h>

#define N_NODES 50000
#define N_EDGES 800000
#define BSHIFT 6                                   // 64 nodes per bucket
#define NBKT   ((N_NODES + 63) >> BSHIFT)          // 782
#define CAP    2048                                // padded slots per bucket
#define CHUNK_EDGES 8192
#define NBIN_BLOCKS ((N_EDGES + CHUNK_EDGES - 1) / CHUNK_EDGES)  // 98
#define NB32   ((N_NODES + 31) / 32)               // 1563 blocks (32 nodes each)
#define N_PAD  50048                               // padded node count (slice regions)

typedef __attribute__((ext_vector_type(8))) short short8;   // 8 bf16 (4 VGPRs)
typedef __attribute__((ext_vector_type(4))) float f32x4;    // MFMA acc

__device__ __forceinline__ int load_idx(const void* ei, int is64, long long pos) {
  return is64 ? (int)((const long long*)ei)[pos] : ((const int*)ei)[pos];
}

// bf16 (RNE) pack/unpack helpers
__device__ __forceinline__ unsigned bfr(float f) {
  unsigned u = __float_as_uint(f);
  return (u + 0x7FFFu + ((u >> 16) & 1u)) >> 16;
}
__device__ __forceinline__ unsigned bfpk(float lo, float hi) {
  return bfr(lo) | (bfr(hi) << 16);
}
#define ACC_BF4(acc, u)                                                    \
  acc.x += __uint_as_float((u).x << 16);                                   \
  acc.y += __uint_as_float((u).x & 0xffff0000u);                           \
  acc.z += __uint_as_float((u).y << 16);                                   \
  acc.w += __uint_as_float((u).y & 0xffff0000u);

// ---------------------------------------------------------------------------
// prep: cast W1/W2 to bf16, native [o][k] layout (W2 padded to 48 rows).
// ---------------------------------------------------------------------------
__global__ __launch_bounds__(256) void prep_kernel(const float* __restrict__ W1,
                                                   const float* __restrict__ W2,
                                                   unsigned short* __restrict__ W1bf,
                                                   unsigned short* __restrict__ W2bf) {
  int j = blockIdx.x * 256 + threadIdx.x;        // [0, 22528)
  if (j < 128 * 128) {
    W1bf[j] = (unsigned short)bfr(W1[j]);
  } else {
    int jj = j - 128 * 128;                      // [0, 6144)
    int c = jj >> 7, k = jj & 127;
    W2bf[jj] = (c < 40) ? (unsigned short)bfr(W2[c * 128 + k]) : 0;
  }
}

// ---------------------------------------------------------------------------
// binPlace2: single-pass bucket partition. Per-block: dtype detect (wave 0),
// LDS bucket histogram, ONE global reservation per bucket, place packed edges
// into padded bucket regions binned[bk*CAP ...]. pk = src|dstlow<<16|bk<<22.
// ---------------------------------------------------------------------------
__global__ __launch_bounds__(256) void binPlace2_kernel(const void* __restrict__ ei,
                                                        int* __restrict__ resv,
                                                        unsigned* __restrict__ binned) {
  __shared__ int cnt[NBKT];
  __shared__ int lbase[NBKT];
  __shared__ int sflag;
  int tid = threadIdx.x;
  if (tid < 64) {
    const long long* e64 = (const long long*)ei;
    long long v = e64[tid];
    unsigned long long m = __ballot(v >= 0 && v < N_NODES);
    if (tid == 0) sflag = (m == ~0ull) ? 1 : 0;
  }
  for (int i = tid; i < NBKT; i += 256) cnt[i] = 0;
  __syncthreads();
  int f = sflag;
  long long base = (long long)blockIdx.x * CHUNK_EDGES;
  unsigned pk[CHUNK_EDGES / 256];
  #pragma unroll
  for (int it = 0; it < CHUNK_EDGES / 256; ++it) {
    long long e = base + it * 256 + tid;
    unsigned p = 0xFFFFFFFFu;
    if (e < N_EDGES) {
      int src = load_idx(ei, f, e);
      int dst = load_idx(ei, f, (long long)N_EDGES + e);
      int bk = dst >> BSHIFT;
      p = (unsigned)src | ((unsigned)(dst & 63) << 16) | ((unsigned)bk << 22);
      atomicAdd(&cnt[bk], 1);
    }
    pk[it] = p;
  }
  __syncthreads();
  for (int i = tid; i < NBKT; i += 256) {
    int c = cnt[i];
    lbase[i] = c ? (i * CAP + atomicAdd(&resv[i], c)) : 0;
    cnt[i] = 0;                                   // reuse as local cursor
  }
  __syncthreads();
  #pragma unroll
  for (int it = 0; it < CHUNK_EDGES / 256; ++it) {
    unsigned p = pk[it];
    if (p != 0xFFFFFFFFu) {
      int bk = p >> 22;
      int off = atomicAdd(&cnt[bk], 1);
      binned[lbase[bk] + off] = p & 0x3FFFFFu;    // src | dstlow<<16
    }
  }
}

// ---------------------------------------------------------------------------
// bucketScan: exclusive scan of 782 bucket totals (resv) -> gbase.
// ---------------------------------------------------------------------------
__global__ __launch_bounds__(1024) void bucketScan_kernel(const int* __restrict__ resv,
                                                          int* __restrict__ gbase,
                                                          int* __restrict__ rowptr) {
  __shared__ int s[1024];
  int tid = threadIdx.x;
  s[tid] = (tid < NBKT) ? resv[tid] : 0;
  __syncthreads();
  for (int off = 1; off < 1024; off <<= 1) {
    int t = (tid >= off) ? s[tid - off] : 0;
    __syncthreads();
    s[tid] += t;
    __syncthreads();
  }
  int excl = (tid == 0) ? 0 : s[tid - 1];
  if (tid < NBKT) gbase[tid] = excl;
  if (tid == NBKT) gbase[NBKT] = s[NBKT - 1];   // == N_EDGES
  if (tid == 0) rowptr[N_NODES] = N_EDGES;
}

// ---------------------------------------------------------------------------
// csrBuild: one block per bucket. LDS node histogram + serial scan -> rowptr;
// compact padded bucket region into col (ushort src).
// ---------------------------------------------------------------------------
__global__ __launch_bounds__(256) void csrBuild_kernel(const unsigned* __restrict__ binned,
                                                       const int* __restrict__ gbase,
                                                       int* __restrict__ rowptr,
                                                       unsigned short* __restrict__ col) {
  __shared__ int ncnt[64];
  __shared__ int ncur[64];
  int b = blockIdx.x, tid = threadIdx.x;
  int gb = gbase[b];
  int c = gbase[b + 1] - gb;
  if (tid < 64) ncnt[tid] = 0;
  __syncthreads();
  const unsigned* bb = binned + (size_t)b * CAP;
  for (int i = tid; i < c; i += 256)
    atomicAdd(&ncnt[(bb[i] >> 16) & 63], 1);
  __syncthreads();
  if (tid == 0) {
    int a = gb;
    #pragma unroll
    for (int j = 0; j < 64; ++j) { int t = ncnt[j]; ncur[j] = a; a += t; }
  }
  __syncthreads();
  int node0 = b << BSHIFT;
  if (tid < 64 && node0 + tid < N_NODES) rowptr[node0 + tid] = ncur[tid];
  __syncthreads();
  for (int i = tid; i < c; i += 256) {
    unsigned p = bb[i];
    int slot = atomicAdd(&ncur[(p >> 16) & 63], 1);
    col[slot] = (unsigned short)(p & 0xFFFFu);
  }
}

// ---------------------------------------------------------------------------
// gather1 (slice-phased, group-per-node): 8 lanes own one node; group loops
// over the node's full edge list, accumulating in-register (no shuffles).
// Y slice-major: 4 regions of [N_PAD][32] bf16 (3.2MB, fits per-XCD L2).
// Grid = 4 slices (slow) x NB32; wave = 8 nodes; edge read = one 64B line.
// ---------------------------------------------------------------------------
__global__ __launch_bounds__(256) void gather1_kernel(const unsigned short* __restrict__ Ys,
                                                      const int* __restrict__ rowptr,
                                                      const unsigned short* __restrict__ col,
                                                      unsigned short* __restrict__ h1bf) {
  int bid = blockIdx.x;
  int slice = bid / NB32;
  int nb = bid - slice * NB32;
  int lane = threadIdx.x & 63;
  int wv = threadIdx.x >> 6;
  int g = lane >> 3, s = lane & 7;
  int w = nb * 32 + wv * 8 + g;
  if (w >= N_NODES) return;
  const uint2* Y2 = (const uint2*)(Ys + (size_t)slice * N_PAD * 32);
  float4 acc = make_float4(0.f, 0.f, 0.f, 0.f);
  {
    uint2 u = Y2[(size_t)w * 8 + s];
    ACC_BF4(acc, u);
  }
  int i = rowptr[w], end = rowptr[w + 1];
  for (; i + 3 < end; i += 4) {
    int s0 = col[i], s1 = col[i + 1], s2 = col[i + 2], s3 = col[i + 3];
    uint2 u0 = Y2[(size_t)s0 * 8 + s];
    uint2 u1 = Y2[(size_t)s1 * 8 + s];
    uint2 u2 = Y2[(size_t)s2 * 8 + s];
    uint2 u3 = Y2[(size_t)s3 * 8 + s];
    ACC_BF4(acc, u0); ACC_BF4(acc, u1); ACC_BF4(acc, u2); ACC_BF4(acc, u3);
  }
  for (; i < end; ++i) {
    uint2 u = Y2[(size_t)col[i] * 8 + s];
    ACC_BF4(acc, u);
  }
  uint2 p;
  p.x = bfpk(fmaxf(acc.x, 0.f), fmaxf(acc.y, 0.f));
  p.y = bfpk(fmaxf(acc.z, 0.f), fmaxf(acc.w, 0.f));
  ((uint2*)h1bf)[(size_t)w * 32 + slice * 8 + s] = p;
}

// ---------------------------------------------------------------------------
// gather2 (group-per-node): 8 lanes own one node; lane s covers uint2 slot s,
// lanes 0-1 also slots 8-9 (80B row). Z is 4MB -> L2-resident. No shuffles.
// ---------------------------------------------------------------------------
__global__ __launch_bounds__(256) void gather2_kernel(const unsigned short* __restrict__ Zbf,
                                                      const int* __restrict__ rowptr,
                                                      const unsigned short* __restrict__ col,
                                                      float* __restrict__ outp) {
  int lane = threadIdx.x & 63;
  int wv = threadIdx.x >> 6;
  int g = lane >> 3, s = lane & 7;
  int w = blockIdx.x * 32 + wv * 8 + g;
  if (w >= N_NODES) return;
  const uint2* Z2 = (const uint2*)Zbf;
  bool ex = s < 2;
  float4 acc = make_float4(0.f, 0.f, 0.f, 0.f);
  float4 acc2 = make_float4(0.f, 0.f, 0.f, 0.f);
  {
    uint2 u = Z2[(size_t)w * 10 + s];
    ACC_BF4(acc, u);
    if (ex) { uint2 v = Z2[(size_t)w * 10 + 8 + s]; ACC_BF4(acc2, v); }
  }
  int i = rowptr[w], end = rowptr[w + 1];
  for (; i + 1 < end; i += 2) {
    int s0 = col[i], s1 = col[i + 1];
    uint2 u0 = Z2[(size_t)s0 * 10 + s];
    uint2 u1 = Z2[(size_t)s1 * 10 + s];
    ACC_BF4(acc, u0); ACC_BF4(acc, u1);
    if (ex) {
      uint2 v0 = Z2[(size_t)s0 * 10 + 8 + s];
      uint2 v1 = Z2[(size_t)s1 * 10 + 8 + s];
      ACC_BF4(acc2, v0); ACC_BF4(acc2, v1);
    }
  }
  for (; i < end; ++i) {
    int s0 = col[i];
    uint2 u0 = Z2[(size_t)s0 * 10 + s];
    ACC_BF4(acc, u0);
    if (ex) { uint2 v0 = Z2[(size_t)s0 * 10 + 8 + s]; ACC_BF4(acc2, v0); }
  }
  float4* o4 = (float4*)(outp + (size_t)w * 40);
  o4[s] = acc;
  if (ex) o4[8 + s] = acc2;
}

// ---------------------------------------------------------------------------
// MFMA GEMM1: Y[n][o] = sum_k x[n][k]*W1[o][k]. Epilogue writes SLICE-MAJOR
// Ys: 4 regions of [N_PAD][32] bf16.
// ---------------------------------------------------------------------------
__global__ __launch_bounds__(256) void gemm1_kernel(const float* __restrict__ xin,
                                                    const unsigned short* __restrict__ W1bf,
                                                    unsigned short* __restrict__ Ysbf) {
  __shared__ unsigned short Ysh[64 * 128];
  int tid = threadIdx.x;
  int wave = tid >> 6, lane = tid & 63;
  int rl = lane & 15, kg = lane >> 4;      // kg = 0..3
  int n0 = blockIdx.x * 64;
  int rowg = n0 + wave * 16 + rl;
  int row = (rowg < N_NODES) ? rowg : (N_NODES - 1);
  f32x4 acc[8];
  #pragma unroll
  for (int t = 0; t < 8; ++t) acc[t] = (f32x4)(0.f);
  #pragma unroll
  for (int kk = 0; kk < 4; ++kk) {
    int k0 = kk * 32 + kg * 8;
    const float* xr = xin + (size_t)row * 128 + k0;
    float4 a0 = *(const float4*)xr;
    float4 a1 = *(const float4*)(xr + 4);
    short8 a;
    a[0] = (short)bfr(a0.x); a[1] = (short)bfr(a0.y);
    a[2] = (short)bfr(a0.z); a[3] = (short)bfr(a0.w);
    a[4] = (short)bfr(a1.x); a[5] = (short)bfr(a1.y);
    a[6] = (short)bfr(a1.z); a[7] = (short)bfr(a1.w);
    #pragma unroll
    for (int t = 0; t < 8; ++t) {
      short8 b = *(const short8*)(W1bf + (t * 16 + rl) * 128 + k0);
      acc[t] = __builtin_amdgcn_mfma_f32_16x16x32_bf16(a, b, acc[t], 0, 0, 0);
    }
  }
  // C/D: col = rl, row = kg*4 + reg (within wave's 16 rows)
  #pragma unroll
  for (int t = 0; t < 8; ++t) {
    #pragma unroll
    for (int reg = 0; reg < 4; ++reg)
      Ysh[(wave * 16 + kg * 4 + reg) * 128 + t * 16 + rl] =
          (unsigned short)bfr(acc[t][reg]);
  }
  __syncthreads();
  int rows = N_NODES - n0; if (rows > 64) rows = 64;
  uint4* dstb = (uint4*)Ysbf;               // slice region = N_PAD*4 uint4
  const uint4* srcb = (const uint4*)Ysh;
  for (int i = tid; i < rows * 16; i += 256) {
    int r = i >> 4, j = i & 15;
    int slice = j >> 2, q = j & 3;
    dstb[(size_t)slice * (N_PAD * 4) + (size_t)(n0 + r) * 4 + q] = srcb[i];
  }
}

// ---------------------------------------------------------------------------
// MFMA GEMM2: Z[n][c] = sum_k h1[n][k]*W2[c][k], c<40 (3 tiles, padded 48).
// ---------------------------------------------------------------------------
__global__ __launch_bounds__(256) void gemm2_kernel(const unsigned short* __restrict__ h1bf,
                                                    const unsigned short* __restrict__ W2bf,
                                                    unsigned short* __restrict__ Zbf) {
  __shared__ unsigned short Zsh[64 * 40];
  int tid = threadIdx.x;
  int wave = tid >> 6, lane = tid & 63;
  int rl = lane & 15, kg = lane >> 4;
  int n0 = blockIdx.x * 64;
  int rowg = n0 + wave * 16 + rl;
  int row = (rowg < N_NODES) ? rowg : (N_NODES - 1);
  f32x4 acc[3];
  #pragma unroll
  for (int t = 0; t < 3; ++t) acc[t] = (f32x4)(0.f);
  #pragma unroll
  for (int kk = 0; kk < 4; ++kk) {
    int k0 = kk * 32 + kg * 8;
    short8 a = *(const short8*)(h1bf + (size_t)row * 128 + k0);
    #pragma unroll
    for (int t = 0; t < 3; ++t) {
      short8 b = *(const short8*)(W2bf + (t * 16 + rl) * 128 + k0);
      acc[t] = __builtin_amdgcn_mfma_f32_16x16x32_bf16(a, b, acc[t], 0, 0, 0);
    }
  }
  #pragma unroll
  for (int t = 0; t < 3; ++t) {
    int c = t * 16 + rl;
    if (c < 40) {
      #pragma unroll
      for (int reg = 0; reg < 4; ++reg)
        Zsh[(wave * 16 + kg * 4 + reg) * 40 + c] = (unsigned short)bfr(acc[t][reg]);
    }
  }
  __syncthreads();
  int rows = N_NODES - n0; if (rows > 64) rows = 64;
  unsigned* dst = (unsigned*)Zbf + (size_t)n0 * 20;
  const unsigned* src = (const unsigned*)Zsh;
  for (int i = tid; i < rows * 20; i += 256) dst[i] = src[i];
}

// ---------------------------------------------------------------------------
extern "C" void kernel_launch(void* const* d_in, const int* in_sizes, int n_in,
                              void* d_out, int out_size, void* d_ws, size_t ws_size,
                              hipStream_t stream) {
  const float* x  = (const float*)d_in[0];
  const void*  ei = d_in[1];
  const float* W1 = (const float*)d_in[2];
  const float* W2 = (const float*)d_in[3];
  float* out = (float*)d_out;

  // ws layout (4-byte units)
  int* resv   = (int*)d_ws;                         // 1024 (memset to 0)
  int* gbase  = resv + 1024;                        // 1024 (783 used)
  int* rowptr = gbase + 1024;                       // 50176 (50001 used)
  unsigned* binned = (unsigned*)(rowptr + 50176);   // NBKT*CAP = 1,601,536
  unsigned short* col  = (unsigned short*)(binned + (size_t)NBKT * CAP); // 800000 ushort
  unsigned short* Ysbf = col + N_EDGES;             // 4 * N_PAD * 32 bf16 (12.8MB)
  unsigned short* h1bf = Ysbf + (size_t)4 * N_PAD * 32;  // 6.4M bf16
  unsigned short* W1bf = h1bf + (size_t)N_NODES * 128;   // 16384 bf16
  unsigned short* W2bf = W1bf + 128 * 128;          // 48*128 bf16 (padded)
  unsigned short* Zbf  = Ysbf;                      // Z reuses dead Ys region

  hipMemsetAsync(resv, 0, 1024 * sizeof(int), stream);
  prep_kernel<<<88, 256, 0, stream>>>(W1, W2, W1bf, W2bf);
  binPlace2_kernel<<<NBIN_BLOCKS, 256, 0, stream>>>(ei, resv, binned);
  bucketScan_kernel<<<1, 1024, 0, stream>>>(resv, gbase, rowptr);
  csrBuild_kernel<<<NBKT, 256, 0, stream>>>(binned, gbase, rowptr, col);

  // Layer 1 (commuted): Ys = x @ W1^T (MFMA, slice-major bf16);
  // h1 = relu(Ys + A*Ys) (bf16, slice-phased group-per-node gather)
  gemm1_kernel<<<(N_NODES + 63) / 64, 256, 0, stream>>>(x, W1bf, Ysbf);
  gather1_kernel<<<4 * NB32, 256, 0, stream>>>(Ysbf, rowptr, col, h1bf);

  // Layer 2 (commuted): Z = h1 @ W2^T (MFMA, bf16) ; out = Z + A*Z (f32)
  gemm2_kernel<<<(N_NODES + 63) / 64, 256, 0, stream>>>(h1bf, W2bf, Zbf);
  gather2_kernel<<<NB32, 256, 0, stream>>>(Zbf, rowptr, col, out);
}

// Round 9
// 116.613 us; speedup vs baseline: 1.4708x; 1.1011x over previous
//
#include <hip/hip_runtime.h>

#define N_NODES 50000
#define N_EDGES 800000
#define BSHIFT 6                                   // 64 nodes per bucket
#define NBKT   ((N_NODES + 63) >> BSHIFT)          // 782
#define CAP    2048                                // padded slots per bucket
#define CHUNK_EDGES 4096
#define NBIN_BLOCKS ((N_EDGES + CHUNK_EDGES - 1) / CHUNK_EDGES)  // 196
#define NB32   ((N_NODES + 31) / 32)               // 1563 blocks (32 nodes each)
#define N_PAD  50048                               // padded node count (slice regions)
#define GEMM1_NB ((N_NODES + 63) / 64)             // 782

typedef __attribute__((ext_vector_type(8))) short short8;   // 8 bf16 (4 VGPRs)
typedef __attribute__((ext_vector_type(4))) float f32x4;    // MFMA acc

__device__ __forceinline__ int load_idx(const void* ei, int is64, long long pos) {
  return is64 ? (int)((const long long*)ei)[pos] : ((const int*)ei)[pos];
}

// bf16 (RNE) pack/unpack helpers
__device__ __forceinline__ unsigned bfr(float f) {
  unsigned u = __float_as_uint(f);
  return (u + 0x7FFFu + ((u >> 16) & 1u)) >> 16;
}
__device__ __forceinline__ unsigned bfpk(float lo, float hi) {
  return bfr(lo) | (bfr(hi) << 16);
}
#define ACC_BF4(acc, u)                                                    \
  acc.x += __uint_as_float((u).x << 16);                                   \
  acc.y += __uint_as_float((u).x & 0xffff0000u);                           \
  acc.z += __uint_as_float((u).y << 16);                                   \
  acc.w += __uint_as_float((u).y & 0xffff0000u);

// ---------------------------------------------------------------------------
// prep: block 0 zeroes resv; blocks 1..88 cast W1/W2 to bf16 (native [o][k],
// W2 padded to 48 rows). Stream order guarantees resv=0 before binPlace2.
// ---------------------------------------------------------------------------
__global__ __launch_bounds__(256) void prep_kernel(const float* __restrict__ W1,
                                                   const float* __restrict__ W2,
                                                   int* __restrict__ resv,
                                                   unsigned short* __restrict__ W1bf,
                                                   unsigned short* __restrict__ W2bf) {
  int b = blockIdx.x, tid = threadIdx.x;
  if (b == 0) {
    ((int4*)resv)[tid] = make_int4(0, 0, 0, 0);   // 1024 ints
    return;
  }
  int j = (b - 1) * 256 + tid;                    // [0, 22528)
  if (j < 128 * 128) {
    W1bf[j] = (unsigned short)bfr(W1[j]);
  } else {
    int jj = j - 128 * 128;                       // [0, 6144)
    int c = jj >> 7, k = jj & 127;
    W2bf[jj] = (c < 40) ? (unsigned short)bfr(W2[c * 128 + k]) : 0;
  }
}

// ---------------------------------------------------------------------------
// binPlace2: single-pass bucket partition. Per-block: dtype detect (wave 0),
// LDS bucket histogram, ONE global reservation per bucket, place packed edges
// into padded bucket regions binned[bk*CAP ...]. pk = src|dstlow<<16|bk<<22.
// 196 blocks x 4096 edges for CU coverage.
// ---------------------------------------------------------------------------
__global__ __launch_bounds__(256) void binPlace2_kernel(const void* __restrict__ ei,
                                                        int* __restrict__ resv,
                                                        unsigned* __restrict__ binned) {
  __shared__ int cnt[NBKT];
  __shared__ int lbase[NBKT];
  __shared__ int sflag;
  int tid = threadIdx.x;
  if (tid < 64) {
    const long long* e64 = (const long long*)ei;
    long long v = e64[tid];
    unsigned long long m = __ballot(v >= 0 && v < N_NODES);
    if (tid == 0) sflag = (m == ~0ull) ? 1 : 0;
  }
  for (int i = tid; i < NBKT; i += 256) cnt[i] = 0;
  __syncthreads();
  int f = sflag;
  long long base = (long long)blockIdx.x * CHUNK_EDGES;
  unsigned pk[CHUNK_EDGES / 256];
  #pragma unroll
  for (int it = 0; it < CHUNK_EDGES / 256; ++it) {
    long long e = base + it * 256 + tid;
    unsigned p = 0xFFFFFFFFu;
    if (e < N_EDGES) {
      int src = load_idx(ei, f, e);
      int dst = load_idx(ei, f, (long long)N_EDGES + e);
      int bk = dst >> BSHIFT;
      p = (unsigned)src | ((unsigned)(dst & 63) << 16) | ((unsigned)bk << 22);
      atomicAdd(&cnt[bk], 1);
    }
    pk[it] = p;
  }
  __syncthreads();
  for (int i = tid; i < NBKT; i += 256) {
    int c = cnt[i];
    lbase[i] = c ? (i * CAP + atomicAdd(&resv[i], c)) : 0;
    cnt[i] = 0;                                   // reuse as local cursor
  }
  __syncthreads();
  #pragma unroll
  for (int it = 0; it < CHUNK_EDGES / 256; ++it) {
    unsigned p = pk[it];
    if (p != 0xFFFFFFFFu) {
      int bk = p >> 22;
      int off = atomicAdd(&cnt[bk], 1);
      binned[lbase[bk] + off] = p & 0x3FFFFFu;    // src | dstlow<<16
    }
  }
}

// ---------------------------------------------------------------------------
// Merged csrBuild + gemm1 (independent work, one dispatch fills the machine).
// Blocks [0, NBKT): csrBuild with INLINE exclusive scan of resv (block b sums
//   resv[0..b) itself; L2-hot). LDS node histogram -> rowptr; compact padded
//   bucket region into col (ushort src).
// Blocks [NBKT, NBKT+GEMM1_NB): MFMA GEMM1 Y[n][o] = sum_k x[n][k]*W1[o][k],
//   epilogue writes SLICE-MAJOR Ys: 4 regions of [N_PAD][32] bf16.
// ---------------------------------------------------------------------------
__global__ __launch_bounds__(256) void csr_gemm1_kernel(const unsigned* __restrict__ binned,
                                                        const int* __restrict__ resv,
                                                        int* __restrict__ rowptr,
                                                        unsigned short* __restrict__ col,
                                                        const float* __restrict__ xin,
                                                        const unsigned short* __restrict__ W1bf,
                                                        unsigned short* __restrict__ Ysbf) {
  __shared__ unsigned short Ysh[64 * 128];
  __shared__ int red[256];
  __shared__ int ncnt[64];
  __shared__ int ncur[64];
  int tid = threadIdx.x;

  if (blockIdx.x < NBKT) {
    // ----- csrBuild part -----
    int b = blockIdx.x;
    // inline exclusive scan: gb = sum resv[0..b)
    int s = 0;
    for (int i = tid; i < b; i += 256) s += resv[i];
    red[tid] = s;
    __syncthreads();
    #pragma unroll
    for (int off = 128; off > 0; off >>= 1) {
      if (tid < off) red[tid] += red[tid + off];
      __syncthreads();
    }
    int gb = red[0];
    int c = resv[b];
    if (tid < 64) ncnt[tid] = 0;
    if (b == 0 && tid == 0) rowptr[N_NODES] = N_EDGES;
    __syncthreads();
    const unsigned* bb = binned + (size_t)b * CAP;
    for (int i = tid; i < c; i += 256)
      atomicAdd(&ncnt[(bb[i] >> 16) & 63], 1);
    __syncthreads();
    if (tid == 0) {
      int a = gb;
      #pragma unroll
      for (int j = 0; j < 64; ++j) { int t = ncnt[j]; ncur[j] = a; a += t; }
    }
    __syncthreads();
    int node0 = b << BSHIFT;
    if (tid < 64 && node0 + tid < N_NODES) rowptr[node0 + tid] = ncur[tid];
    __syncthreads();
    for (int i = tid; i < c; i += 256) {
      unsigned p = bb[i];
      int slot = atomicAdd(&ncur[(p >> 16) & 63], 1);
      col[slot] = (unsigned short)(p & 0xFFFFu);
    }
    return;
  }

  // ----- gemm1 part -----
  int wave = tid >> 6, lane = tid & 63;
  int rl = lane & 15, kg = lane >> 4;      // kg = 0..3
  int n0 = (blockIdx.x - NBKT) * 64;
  int rowg = n0 + wave * 16 + rl;
  int row = (rowg < N_NODES) ? rowg : (N_NODES - 1);
  f32x4 acc[8];
  #pragma unroll
  for (int t = 0; t < 8; ++t) acc[t] = (f32x4)(0.f);
  #pragma unroll
  for (int kk = 0; kk < 4; ++kk) {
    int k0 = kk * 32 + kg * 8;
    const float* xr = xin + (size_t)row * 128 + k0;
    float4 a0 = *(const float4*)xr;
    float4 a1 = *(const float4*)(xr + 4);
    short8 a;
    a[0] = (short)bfr(a0.x); a[1] = (short)bfr(a0.y);
    a[2] = (short)bfr(a0.z); a[3] = (short)bfr(a0.w);
    a[4] = (short)bfr(a1.x); a[5] = (short)bfr(a1.y);
    a[6] = (short)bfr(a1.z); a[7] = (short)bfr(a1.w);
    #pragma unroll
    for (int t = 0; t < 8; ++t) {
      short8 b = *(const short8*)(W1bf + (t * 16 + rl) * 128 + k0);
      acc[t] = __builtin_amdgcn_mfma_f32_16x16x32_bf16(a, b, acc[t], 0, 0, 0);
    }
  }
  // C/D: col = rl, row = kg*4 + reg (within wave's 16 rows)
  #pragma unroll
  for (int t = 0; t < 8; ++t) {
    #pragma unroll
    for (int reg = 0; reg < 4; ++reg)
      Ysh[(wave * 16 + kg * 4 + reg) * 128 + t * 16 + rl] =
          (unsigned short)bfr(acc[t][reg]);
  }
  __syncthreads();
  int rows = N_NODES - n0; if (rows > 64) rows = 64;
  uint4* dstb = (uint4*)Ysbf;               // slice region = N_PAD*4 uint4
  const uint4* srcb = (const uint4*)Ysh;
  for (int i = tid; i < rows * 16; i += 256) {
    int r = i >> 4, j = i & 15;
    int slice = j >> 2, q = j & 3;
    dstb[(size_t)slice * (N_PAD * 4) + (size_t)(n0 + r) * 4 + q] = srcb[i];
  }
}

// ---------------------------------------------------------------------------
// gather1 (slice-phased, group-per-node): 8 lanes own one node; group loops
// over the node's full edge list, accumulating in-register (no shuffles).
// Y slice-major: 4 regions of [N_PAD][32] bf16 (3.2MB, fits per-XCD L2).
// Grid = 4 slices (slow) x NB32; wave = 8 nodes; edge read = one 64B line.
// ---------------------------------------------------------------------------
__global__ __launch_bounds__(256) void gather1_kernel(const unsigned short* __restrict__ Ys,
                                                      const int* __restrict__ rowptr,
                                                      const unsigned short* __restrict__ col,
                                                      unsigned short* __restrict__ h1bf) {
  int bid = blockIdx.x;
  int slice = bid / NB32;
  int nb = bid - slice * NB32;
  int lane = threadIdx.x & 63;
  int wv = threadIdx.x >> 6;
  int g = lane >> 3, s = lane & 7;
  int w = nb * 32 + wv * 8 + g;
  if (w >= N_NODES) return;
  const uint2* Y2 = (const uint2*)(Ys + (size_t)slice * N_PAD * 32);
  float4 acc = make_float4(0.f, 0.f, 0.f, 0.f);
  {
    uint2 u = Y2[(size_t)w * 8 + s];
    ACC_BF4(acc, u);
  }
  int i = rowptr[w], end = rowptr[w + 1];
  for (; i + 3 < end; i += 4) {
    int s0 = col[i], s1 = col[i + 1], s2 = col[i + 2], s3 = col[i + 3];
    uint2 u0 = Y2[(size_t)s0 * 8 + s];
    uint2 u1 = Y2[(size_t)s1 * 8 + s];
    uint2 u2 = Y2[(size_t)s2 * 8 + s];
    uint2 u3 = Y2[(size_t)s3 * 8 + s];
    ACC_BF4(acc, u0); ACC_BF4(acc, u1); ACC_BF4(acc, u2); ACC_BF4(acc, u3);
  }
  for (; i < end; ++i) {
    uint2 u = Y2[(size_t)col[i] * 8 + s];
    ACC_BF4(acc, u);
  }
  uint2 p;
  p.x = bfpk(fmaxf(acc.x, 0.f), fmaxf(acc.y, 0.f));
  p.y = bfpk(fmaxf(acc.z, 0.f), fmaxf(acc.w, 0.f));
  ((uint2*)h1bf)[(size_t)w * 32 + slice * 8 + s] = p;
}

// ---------------------------------------------------------------------------
// gather2 (group-per-node): 8 lanes own one node; lane s covers uint2 slot s,
// lanes 0-1 also slots 8-9 (80B row). Z is 4MB -> L2-resident. No shuffles.
// ---------------------------------------------------------------------------
__global__ __launch_bounds__(256) void gather2_kernel(const unsigned short* __restrict__ Zbf,
                                                      const int* __restrict__ rowptr,
                                                      const unsigned short* __restrict__ col,
                                                      float* __restrict__ outp) {
  int lane = threadIdx.x & 63;
  int wv = threadIdx.x >> 6;
  int g = lane >> 3, s = lane & 7;
  int w = blockIdx.x * 32 + wv * 8 + g;
  if (w >= N_NODES) return;
  const uint2* Z2 = (const uint2*)Zbf;
  bool ex = s < 2;
  float4 acc = make_float4(0.f, 0.f, 0.f, 0.f);
  float4 acc2 = make_float4(0.f, 0.f, 0.f, 0.f);
  {
    uint2 u = Z2[(size_t)w * 10 + s];
    ACC_BF4(acc, u);
    if (ex) { uint2 v = Z2[(size_t)w * 10 + 8 + s]; ACC_BF4(acc2, v); }
  }
  int i = rowptr[w], end = rowptr[w + 1];
  for (; i + 1 < end; i += 2) {
    int s0 = col[i], s1 = col[i + 1];
    uint2 u0 = Z2[(size_t)s0 * 10 + s];
    uint2 u1 = Z2[(size_t)s1 * 10 + s];
    ACC_BF4(acc, u0); ACC_BF4(acc, u1);
    if (ex) {
      uint2 v0 = Z2[(size_t)s0 * 10 + 8 + s];
      uint2 v1 = Z2[(size_t)s1 * 10 + 8 + s];
      ACC_BF4(acc2, v0); ACC_BF4(acc2, v1);
    }
  }
  for (; i < end; ++i) {
    int s0 = col[i];
    uint2 u0 = Z2[(size_t)s0 * 10 + s];
    ACC_BF4(acc, u0);
    if (ex) { uint2 v0 = Z2[(size_t)s0 * 10 + 8 + s]; ACC_BF4(acc2, v0); }
  }
  float4* o4 = (float4*)(outp + (size_t)w * 40);
  o4[s] = acc;
  if (ex) o4[8 + s] = acc2;
}

// ---------------------------------------------------------------------------
// MFMA GEMM2: Z[n][c] = sum_k h1[n][k]*W2[c][k], c<40 (3 tiles, padded 48).
// ---------------------------------------------------------------------------
__global__ __launch_bounds__(256) void gemm2_kernel(const unsigned short* __restrict__ h1bf,
                                                    const unsigned short* __restrict__ W2bf,
                                                    unsigned short* __restrict__ Zbf) {
  __shared__ unsigned short Zsh[64 * 40];
  int tid = threadIdx.x;
  int wave = tid >> 6, lane = tid & 63;
  int rl = lane & 15, kg = lane >> 4;
  int n0 = blockIdx.x * 64;
  int rowg = n0 + wave * 16 + rl;
  int row = (rowg < N_NODES) ? rowg : (N_NODES - 1);
  f32x4 acc[3];
  #pragma unroll
  for (int t = 0; t < 3; ++t) acc[t] = (f32x4)(0.f);
  #pragma unroll
  for (int kk = 0; kk < 4; ++kk) {
    int k0 = kk * 32 + kg * 8;
    short8 a = *(const short8*)(h1bf + (size_t)row * 128 + k0);
    #pragma unroll
    for (int t = 0; t < 3; ++t) {
      short8 b = *(const short8*)(W2bf + (t * 16 + rl) * 128 + k0);
      acc[t] = __builtin_amdgcn_mfma_f32_16x16x32_bf16(a, b, acc[t], 0, 0, 0);
    }
  }
  #pragma unroll
  for (int t = 0; t < 3; ++t) {
    int c = t * 16 + rl;
    if (c < 40) {
      #pragma unroll
      for (int reg = 0; reg < 4; ++reg)
        Zsh[(wave * 16 + kg * 4 + reg) * 40 + c] = (unsigned short)bfr(acc[t][reg]);
    }
  }
  __syncthreads();
  int rows = N_NODES - n0; if (rows > 64) rows = 64;
  unsigned* dst = (unsigned*)Zbf + (size_t)n0 * 20;
  const unsigned* src = (const unsigned*)Zsh;
  for (int i = tid; i < rows * 20; i += 256) dst[i] = src[i];
}

// ---------------------------------------------------------------------------
extern "C" void kernel_launch(void* const* d_in, const int* in_sizes, int n_in,
                              void* d_out, int out_size, void* d_ws, size_t ws_size,
                              hipStream_t stream) {
  const float* x  = (const float*)d_in[0];
  const void*  ei = d_in[1];
  const float* W1 = (const float*)d_in[2];
  const float* W2 = (const float*)d_in[3];
  float* out = (float*)d_out;

  // ws layout (4-byte units)
  int* resv   = (int*)d_ws;                         // 1024 (zeroed by prep blk 0)
  int* rowptr = resv + 1024;                        // 50176 (50001 used)
  unsigned* binned = (unsigned*)(rowptr + 50176);   // NBKT*CAP = 1,601,536
  unsigned short* col  = (unsigned short*)(binned + (size_t)NBKT * CAP); // 800000 ushort
  unsigned short* Ysbf = col + N_EDGES;             // 4 * N_PAD * 32 bf16 (12.8MB)
  unsigned short* h1bf = Ysbf + (size_t)4 * N_PAD * 32;  // 6.4M bf16
  unsigned short* W1bf = h1bf + (size_t)N_NODES * 128;   // 16384 bf16
  unsigned short* W2bf = W1bf + 128 * 128;          // 48*128 bf16 (padded)
  unsigned short* Zbf  = Ysbf;                      // Z reuses dead Ys region

  prep_kernel<<<89, 256, 0, stream>>>(W1, W2, resv, W1bf, W2bf);
  binPlace2_kernel<<<NBIN_BLOCKS, 256, 0, stream>>>(ei, resv, binned);
  csr_gemm1_kernel<<<NBKT + GEMM1_NB, 256, 0, stream>>>(binned, resv, rowptr, col,
                                                        x, W1bf, Ysbf);
  gather1_kernel<<<4 * NB32, 256, 0, stream>>>(Ysbf, rowptr, col, h1bf);
  gemm2_kernel<<<GEMM1_NB, 256, 0, stream>>>(h1bf, W2bf, Zbf);
  gather2_kernel<<<NB32, 256, 0, stream>>>(Zbf, rowptr, col, out);
}